// Round 8
// baseline (2810.733 us; speedup 1.0000x reference)
//
#include <hip/hip_runtime.h>

// Problem constants (B,S,D=16,2048,256; K codebooks=8, CD=1024)
#define DD    256
#define KST   8
#define CDN   1024
#define NROWS 32768          // B*S
#define ROWS  64             // rows (tokens) per block (8 waves x 8 rows)
#define AST   64             // a_t row stride

// Transposed codebook, float2-granular:
// cbT[s][c2][j][2] = cb[s][j][2*c2 + 0..1], c2 = 0..127.
// Per-chunk B loads are lane-consecutive 8B -> perfectly coalesced.
__device__ float cbT_buf[(size_t)KST * 128 * CDN * 2];   // 8 MB static

__device__ __forceinline__ bool better(float a, int ja, float b, int jb_) {
    return (a < b) || (a == b && ja < jb_);
}

// ---------------------------------------------------------------------------
// numpy AVX512 pairwise sum-of-squares over 256 values (bit-emulated).
template <typename F>
__device__ __forceinline__ float np_sumsq_256(F ld) {
    float Sv = 0.f;
#pragma unroll
    for (int blk = 0; blk < 2; ++blk) {
        const int o = blk * 128;
        float w[16];
#pragma unroll
        for (int l = 0; l < 16; ++l) {
            float v[8];
#pragma unroll
            for (int j = 0; j < 8; ++j) {
                float xv = ld(o + 16 * j + l);
                v[j] = __fmul_rn(xv, xv);
            }
            float a01 = __fadd_rn(v[0], v[1]);
            float a23 = __fadd_rn(v[2], v[3]);
            float a45 = __fadd_rn(v[4], v[5]);
            float a67 = __fadd_rn(v[6], v[7]);
            w[l] = __fadd_rn(__fadd_rn(a01, a23), __fadd_rn(a45, a67));
        }
        float t8[8];
#pragma unroll
        for (int l = 0; l < 8; ++l) t8[l] = __fadd_rn(w[l], w[l + 8]);
        float t4[4];
#pragma unroll
        for (int l = 0; l < 4; ++l) t4[l] = __fadd_rn(t8[l], t8[l + 4]);
        float t2_0 = __fadd_rn(t4[0], t4[2]);
        float t2_1 = __fadd_rn(t4[1], t4[3]);
        float bs = __fadd_rn(t2_0, t2_1);
        Sv = (blk == 0) ? bs : __fadd_rn(Sv, bs);
    }
    return Sv;
}

// ---------------------------------------------------------------------------
__global__ __launch_bounds__(256) void norms_kernel(const float* __restrict__ cb,
                                                    float* __restrict__ n32) {
    int j = blockIdx.x * 256 + threadIdx.x;   // 0..8191
    const float* p = cb + (size_t)j * DD;
    n32[j] = np_sumsq_256([&](int i) { return p[i]; });
}

// ---------------------------------------------------------------------------
// One-time codebook transpose into cbT_buf (float2 granules).
// idx = s*131072 + c2*1024 + j; writes coalesced 8B.
__global__ __launch_bounds__(256) void tr_kernel(const float* __restrict__ cb) {
    int idx = blockIdx.x * 256 + threadIdx.x;  // 0 .. 1048575
    int j  = idx & 1023;
    int c2 = (idx >> 10) & 127;
    int s  = idx >> 17;
    float2 v = *(const float2*)(cb + ((size_t)(s * CDN + j) * DD) + c2 * 2);
    *(float2*)(cbT_buf + (size_t)idx * 2) = v;
}

// ---------------------------------------------------------------------------
// Fused RVQ — numpy-fp32 emulation, TLP-scaled structure.
// Rounds 4-7 measured ~2 resident blocks/CU (2 waves/SIMD) at VGPR 104-112:
// FMA issue = 35% of wall, other VALU 14%, 51% stall-with-no-issuable-wave.
// The per-wave pipeline (A/B prefetch) is fine; TLP is the limiter.
// This round: 512-thread blocks (8 waves x 8 rows = 64 rows/block), grid=512
// = exactly 2 blocks/CU -> 16 waves/CU = 4 waves/SIMD (VGPR 4x112=448<=512,
// LDS 2x66.5KB=133KB<=160KB). Per-wave code is unchanged from round 7:
// wave-local rows, pipelined A broadcasts + B ping-pong, wave-local argmin,
// 2 barriers/stage. Per-(row,cw) dot chain stays single-accumulator FMA with
// k ascending -> scores and indices bit-identical.
__global__ __launch_bounds__(512, 4) void rvq_kernel(const float* __restrict__ x,
                                                     const float* __restrict__ cbs,
                                                     const float* __restrict__ n32,
                                                     float* __restrict__ out) {
    __shared__ __align__(16) float a_t[DD][AST];   // 65536 B residual^T
    __shared__ float rowS[ROWS];                   // np sum(res*res) per row
    __shared__ float bestS[ROWS];                  // running best score per row
    __shared__ int   bestI[ROWS];                  // running best index per row
    __shared__ float wred[8];

    const int tid  = threadIdx.x;
    const int base = blockIdx.x * ROWS;
    const int cg   = tid & 63;            // lane: codeword group
    const int ty   = tid >> 6;            // wave id = row-group (8 rows), 0..7
    const int row0 = ty * 8;
    const int urow = tid & 63;            // update row (64 rows)
    const int ug   = tid >> 6;            // owned 32-dim segment (8 segs)

    for (int i = tid; i < ROWS * DD / 4; i += 512) {
        int row = i >> 6;                 // 0..63
        int dq  = i & 63;                 // 0..63 (float4s per row)
        float4 v = ((const float4*)(x + (size_t)(base + row) * DD))[dq];
        int d = dq * 4;
        a_t[d + 0][row] = v.x; a_t[d + 1][row] = v.y;
        a_t[d + 2][row] = v.z; a_t[d + 3][row] = v.w;
    }

    float loss_acc = 0.f;

    for (int s = 0; s < KST; ++s) {
        const float* cb  = cbs + (size_t)s * CDN * DD;
        const float* nr  = n32 + s * CDN;
        const float* cts = cbT_buf + ((size_t)s << 18);   // s * 128*1024*2
        __syncthreads();                  // (A) a_t stable; prev bestI reads done

        // np-AVX512 S = sum(res*res): wave ty's lanes 0-7 do rows row0..row0+7
        // (identical per-row serial code path -> bit-exact; wave-local).
        if (cg < 8) {
            int row = row0 + cg;
            rowS[row] = np_sumsq_256([&](int i) { return a_t[i][row]; });
            bestS[row] = 3.4e38f;
            bestI[row] = 0x7ffffff;
        }

        for (int h = 0; h < 2; ++h) {
            float acc[8][8];              // [slot][r]
#pragma unroll
            for (int sl = 0; sl < 8; ++sl)
#pragma unroll
                for (int r = 0; r < 8; ++r) acc[sl][r] = 0.f;

            // B base for this lane: element (c2*1024 + h*512 + slot*64 + cg)
            const float* bp = cts + ((size_t)(h * 512) + cg) * 2;

            float2 bA_[8], bB_[8];        // B ping-pong (chunk granularity)
            float  xaR[8], yaR[8];        // pipelined A broadcasts

            auto LOADB = [&](float2* dst, int c) {
                const float* q = bp + (size_t)c * 2048;
#pragma unroll
                for (int sl = 0; sl < 8; ++sl)
                    dst[sl] = *(const float2*)(q + sl * 128);
            };
            auto LOADA = [&](float* dst, int kk) {
                float4 p0 = *(const float4*)&a_t[kk][row0];
                float4 p1 = *(const float4*)&a_t[kk][row0 + 4];
                dst[0] = p0.x; dst[1] = p0.y; dst[2] = p0.z; dst[3] = p0.w;
                dst[4] = p1.x; dst[5] = p1.y; dst[6] = p1.z; dst[7] = p1.w;
            };
            auto FMAX = [&](const float2* b, const float* a) {
#pragma unroll
                for (int sl = 0; sl < 8; ++sl)
#pragma unroll
                    for (int r = 0; r < 8; ++r)
                        acc[sl][r] = __builtin_fmaf(b[sl].x, a[r], acc[sl][r]);
            };
            auto FMAY = [&](const float2* b, const float* a) {
#pragma unroll
                for (int sl = 0; sl < 8; ++sl)
#pragma unroll
                    for (int r = 0; r < 8; ++r)
                        acc[sl][r] = __builtin_fmaf(b[sl].y, a[r], acc[sl][r]);
            };

            LOADB(bA_, 0);
            LOADA(xaR, 0);
#pragma unroll 1
            for (int c2 = 0; c2 < 128; c2 += 2) {
                LOADA(yaR, 2 * c2 + 1);   // ya(c2): used after 64 x-FMAs
                LOADB(bB_, c2 + 1);       // B(c2+1): used next chunk
                FMAX(bA_, xaR);           // k = 2*c2
                LOADA(xaR, 2 * c2 + 2);   // xa(c2+1): used after 64 y-FMAs
                FMAY(bA_, yaR);           // k = 2*c2+1
                LOADA(yaR, 2 * c2 + 3);   // ya(c2+1)
                {
                    int cn = (c2 + 2 < 128) ? (c2 + 2) : 127;   // branchless guard
                    LOADB(bA_, cn);       // B(c2+2)
                }
                FMAX(bB_, xaR);           // k = 2*c2+2
                {
                    int kn = (2 * c2 + 4 < 256) ? (2 * c2 + 4) : 254;
                    LOADA(xaR, kn);       // xa(c2+2)
                }
                FMAY(bB_, yaR);           // k = 2*c2+3
            }

            // np-composed score + per-row 64-lane argmin butterfly
            float nrv[8];
#pragma unroll
            for (int sl = 0; sl < 8; ++sl) nrv[sl] = nr[h * 512 + sl * 64 + cg];
#pragma unroll
            for (int r = 0; r < 8; ++r) {
                int row = row0 + r;
                float Sr = rowS[row];     // wave-local (written by own lanes 0-7)
                float t1 = 3.4e38f; int u1 = 0x7ffffff;
#pragma unroll
                for (int sl = 0; sl < 8; ++sl) {
                    int j = h * 512 + sl * 64 + cg;
                    float m2 = __fmul_rn(2.f, acc[sl][r]);
                    float sc2 = __fadd_rn(__fsub_rn(Sr, m2), nrv[sl]);
                    if (better(sc2, j, t1, u1)) { t1 = sc2; u1 = j; }
                }
#pragma unroll
                for (int off = 32; off >= 1; off >>= 1) {
                    float ob = __shfl_xor(t1, off, 64);
                    int   oj = __shfl_xor(u1, off, 64);
                    if (better(ob, oj, t1, u1)) { t1 = ob; u1 = oj; }
                }
                if (cg == r) {            // this wave owns the row: no merge
                    if (better(t1, u1, bestS[row], bestI[row])) {
                        bestS[row] = t1; bestI[row] = u1;
                    }
                }
            }
        }

        if (cg < 8) {                     // index output, wave-local rows
            int row = row0 + cg;
            out[2 + (size_t)(base + row) * KST + s] = (float)bestI[row];
        }
        __syncthreads();                  // (C) bestI final for all rows

        // residual update + loss (elementwise fp32; banks 2-way via remap)
        {
            int bi = bestI[urow];
            const float4* cp = (const float4*)(cb + (size_t)bi * DD + ug * 32);
#pragma unroll
            for (int dq = 0; dq < 8; ++dq) {
                float4 v = cp[dq];
                int d = ug * 32 + dq * 4;
                float e0 = __fsub_rn(a_t[d + 0][urow], v.x); a_t[d + 0][urow] = e0;
                float e1 = __fsub_rn(a_t[d + 1][urow], v.y); a_t[d + 1][urow] = e1;
                float e2 = __fsub_rn(a_t[d + 2][urow], v.z); a_t[d + 2][urow] = e2;
                float e3 = __fsub_rn(a_t[d + 3][urow], v.w); a_t[d + 3][urow] = e3;
                loss_acc += e0 * e0 + e1 * e1 + e2 * e2 + e3 * e3;
            }
        }
    }
    __syncthreads();                      // (E) a_t final

    // ---- outputs ---- (indices already written per stage)
    float* q = out + 2 + (size_t)NROWS * KST;
    for (int i = tid; i < ROWS * DD / 4; i += 512) {
        int row = i >> 6, dq = i & 63, d = dq * 4;
        float4 xv = ((const float4*)(x + (size_t)(base + row) * DD))[dq];
        float4 o;
        o.x = xv.x - a_t[d + 0][row];
        o.y = xv.y - a_t[d + 1][row];
        o.z = xv.z - a_t[d + 2][row];
        o.w = xv.w - a_t[d + 3][row];
        ((float4*)(q + (size_t)(base + row) * DD))[dq] = o;
    }
#pragma unroll
    for (int off = 32; off >= 1; off >>= 1) loss_acc += __shfl_down(loss_acc, off, 64);
    if ((tid & 63) == 0) wred[tid >> 6] = loss_acc;
    __syncthreads();
    if (tid == 0) {
        float t = ((wred[0] + wred[1]) + (wred[2] + wred[3]))
                + ((wred[4] + wred[5]) + (wred[6] + wred[7]));
        t *= (1.f / ((float)NROWS * (float)DD));
        atomicAdd(out + 0, t);
        atomicAdd(out + 1, t);
    }
}

// ---------------------------------------------------------------------------
extern "C" void kernel_launch(void* const* d_in, const int* in_sizes, int n_in,
                              void* d_out, int out_size, void* d_ws, size_t ws_size,
                              hipStream_t stream) {
    const float* x   = (const float*)d_in[0];   // [16,2048,256] fp32
    const float* cbs = (const float*)d_in[1];   // [8,1024,256] fp32
    float* out = (float*)d_out;
    float* n32 = (float*)d_ws;                  // 8192 floats

    hipMemsetAsync(d_out, 0, 2 * sizeof(float), stream);
    tr_kernel<<<4096, 256, 0, stream>>>(cbs);
    norms_kernel<<<32, 256, 0, stream>>>(cbs, n32);
    rvq_kernel<<<NROWS / ROWS, 512, 0, stream>>>(x, cbs, n32, out);
}

// Round 9
// 2180.120 us; speedup vs baseline: 1.2893x; 1.2893x over previous
//
#include <hip/hip_runtime.h>

// Problem constants (B,S,D=16,2048,256; K codebooks=8, CD=1024)
#define DD    256
#define KST   8
#define CDN   1024
#define NROWS 32768          // B*S
#define ROWS  64             // rows (tokens) per block (8 waves x 8 rows)
#define AST   64             // a_t row stride

// Transposed codebook, float2-granular:
// cbT[s][c2][j][2] = cb[s][j][2*c2 + 0..1], c2 = 0..127.
// Per-chunk B loads are lane-consecutive 8B -> perfectly coalesced.
__device__ float cbT_buf[(size_t)KST * 128 * CDN * 2];   // 8 MB static

__device__ __forceinline__ bool better(float a, int ja, float b, int jb_) {
    return (a < b) || (a == b && ja < jb_);
}

// ---------------------------------------------------------------------------
// numpy AVX512 pairwise sum-of-squares over 256 values (bit-emulated).
template <typename F>
__device__ __forceinline__ float np_sumsq_256(F ld) {
    float Sv = 0.f;
#pragma unroll
    for (int blk = 0; blk < 2; ++blk) {
        const int o = blk * 128;
        float w[16];
#pragma unroll
        for (int l = 0; l < 16; ++l) {
            float v[8];
#pragma unroll
            for (int j = 0; j < 8; ++j) {
                float xv = ld(o + 16 * j + l);
                v[j] = __fmul_rn(xv, xv);
            }
            float a01 = __fadd_rn(v[0], v[1]);
            float a23 = __fadd_rn(v[2], v[3]);
            float a45 = __fadd_rn(v[4], v[5]);
            float a67 = __fadd_rn(v[6], v[7]);
            w[l] = __fadd_rn(__fadd_rn(a01, a23), __fadd_rn(a45, a67));
        }
        float t8[8];
#pragma unroll
        for (int l = 0; l < 8; ++l) t8[l] = __fadd_rn(w[l], w[l + 8]);
        float t4[4];
#pragma unroll
        for (int l = 0; l < 4; ++l) t4[l] = __fadd_rn(t8[l], t8[l + 4]);
        float t2_0 = __fadd_rn(t4[0], t4[2]);
        float t2_1 = __fadd_rn(t4[1], t4[3]);
        float bs = __fadd_rn(t2_0, t2_1);
        Sv = (blk == 0) ? bs : __fadd_rn(Sv, bs);
    }
    return Sv;
}

// ---------------------------------------------------------------------------
__global__ __launch_bounds__(256) void norms_kernel(const float* __restrict__ cb,
                                                    float* __restrict__ n32) {
    int j = blockIdx.x * 256 + threadIdx.x;   // 0..8191
    const float* p = cb + (size_t)j * DD;
    n32[j] = np_sumsq_256([&](int i) { return p[i]; });
}

// ---------------------------------------------------------------------------
// One-time codebook transpose into cbT_buf (float2 granules).
// idx = s*131072 + c2*1024 + j; writes coalesced 8B.
__global__ __launch_bounds__(256) void tr_kernel(const float* __restrict__ cb) {
    int idx = blockIdx.x * 256 + threadIdx.x;  // 0 .. 1048575
    int j  = idx & 1023;
    int c2 = (idx >> 10) & 127;
    int s  = idx >> 17;
    float2 v = *(const float2*)(cb + ((size_t)(s * CDN + j) * DD) + c2 * 2);
    *(float2*)(cbT_buf + (size_t)idx * 2) = v;
}

// ---------------------------------------------------------------------------
// Fused RVQ — numpy-fp32 emulation, TLP-scaled structure.
// Round 8 proved the 512-thread/8-wave block delivers the residency (occ 42%
// = 2 blocks x 8 waves per CU) but __launch_bounds__(512,4) clamped VGPR to
// 64 and spilled acc[8][8] (WRITE_SIZE 40->344 MB). Empirical cap pattern:
// (256,3)->84, (256,4)->64, (512,4)->64, (256,2)->128. (512,2) caps at 128,
// fitting the measured 112-reg body with no spill while still allowing
// 2 blocks/CU (LDS 2x66560=133KB<=160KB; VGPR 4 waves/SIMD x 112 <= 512).
// Per-wave code identical to round 7: wave-local 8 rows, pipelined A
// broadcasts + B ping-pong, wave-local argmin, 2 barriers/stage.
// Per-(row,cw) dot chain stays single-accumulator FMA with k ascending ->
// scores and indices bit-identical.
__global__ __launch_bounds__(512, 2) void rvq_kernel(const float* __restrict__ x,
                                                     const float* __restrict__ cbs,
                                                     const float* __restrict__ n32,
                                                     float* __restrict__ out) {
    __shared__ __align__(16) float a_t[DD][AST];   // 65536 B residual^T
    __shared__ float rowS[ROWS];                   // np sum(res*res) per row
    __shared__ float bestS[ROWS];                  // running best score per row
    __shared__ int   bestI[ROWS];                  // running best index per row
    __shared__ float wred[8];

    const int tid  = threadIdx.x;
    const int base = blockIdx.x * ROWS;
    const int cg   = tid & 63;            // lane: codeword group
    const int ty   = tid >> 6;            // wave id = row-group (8 rows), 0..7
    const int row0 = ty * 8;
    const int urow = tid & 63;            // update row (64 rows)
    const int ug   = tid >> 6;            // owned 32-dim segment (8 segs)

    for (int i = tid; i < ROWS * DD / 4; i += 512) {
        int row = i >> 6;                 // 0..63
        int dq  = i & 63;                 // 0..63 (float4s per row)
        float4 v = ((const float4*)(x + (size_t)(base + row) * DD))[dq];
        int d = dq * 4;
        a_t[d + 0][row] = v.x; a_t[d + 1][row] = v.y;
        a_t[d + 2][row] = v.z; a_t[d + 3][row] = v.w;
    }

    float loss_acc = 0.f;

    for (int s = 0; s < KST; ++s) {
        const float* cb  = cbs + (size_t)s * CDN * DD;
        const float* nr  = n32 + s * CDN;
        const float* cts = cbT_buf + ((size_t)s << 18);   // s * 128*1024*2
        __syncthreads();                  // (A) a_t stable; prev bestI reads done

        // np-AVX512 S = sum(res*res): wave ty's lanes 0-7 do rows row0..row0+7
        // (identical per-row serial code path -> bit-exact; wave-local).
        if (cg < 8) {
            int row = row0 + cg;
            rowS[row] = np_sumsq_256([&](int i) { return a_t[i][row]; });
            bestS[row] = 3.4e38f;
            bestI[row] = 0x7ffffff;
        }

        for (int h = 0; h < 2; ++h) {
            float acc[8][8];              // [slot][r]
#pragma unroll
            for (int sl = 0; sl < 8; ++sl)
#pragma unroll
                for (int r = 0; r < 8; ++r) acc[sl][r] = 0.f;

            // B base for this lane: element (c2*1024 + h*512 + slot*64 + cg)
            const float* bp = cts + ((size_t)(h * 512) + cg) * 2;

            float2 bA_[8], bB_[8];        // B ping-pong (chunk granularity)
            float  xaR[8], yaR[8];        // pipelined A broadcasts

            auto LOADB = [&](float2* dst, int c) {
                const float* q = bp + (size_t)c * 2048;
#pragma unroll
                for (int sl = 0; sl < 8; ++sl)
                    dst[sl] = *(const float2*)(q + sl * 128);
            };
            auto LOADA = [&](float* dst, int kk) {
                float4 p0 = *(const float4*)&a_t[kk][row0];
                float4 p1 = *(const float4*)&a_t[kk][row0 + 4];
                dst[0] = p0.x; dst[1] = p0.y; dst[2] = p0.z; dst[3] = p0.w;
                dst[4] = p1.x; dst[5] = p1.y; dst[6] = p1.z; dst[7] = p1.w;
            };
            auto FMAX = [&](const float2* b, const float* a) {
#pragma unroll
                for (int sl = 0; sl < 8; ++sl)
#pragma unroll
                    for (int r = 0; r < 8; ++r)
                        acc[sl][r] = __builtin_fmaf(b[sl].x, a[r], acc[sl][r]);
            };
            auto FMAY = [&](const float2* b, const float* a) {
#pragma unroll
                for (int sl = 0; sl < 8; ++sl)
#pragma unroll
                    for (int r = 0; r < 8; ++r)
                        acc[sl][r] = __builtin_fmaf(b[sl].y, a[r], acc[sl][r]);
            };

            LOADB(bA_, 0);
            LOADA(xaR, 0);
#pragma unroll 1
            for (int c2 = 0; c2 < 128; c2 += 2) {
                LOADA(yaR, 2 * c2 + 1);   // ya(c2): used after 64 x-FMAs
                LOADB(bB_, c2 + 1);       // B(c2+1): used next chunk
                FMAX(bA_, xaR);           // k = 2*c2
                LOADA(xaR, 2 * c2 + 2);   // xa(c2+1): used after 64 y-FMAs
                FMAY(bA_, yaR);           // k = 2*c2+1
                LOADA(yaR, 2 * c2 + 3);   // ya(c2+1)
                {
                    int cn = (c2 + 2 < 128) ? (c2 + 2) : 127;   // branchless guard
                    LOADB(bA_, cn);       // B(c2+2)
                }
                FMAX(bB_, xaR);           // k = 2*c2+2
                {
                    int kn = (2 * c2 + 4 < 256) ? (2 * c2 + 4) : 254;
                    LOADA(xaR, kn);       // xa(c2+2)
                }
                FMAY(bB_, yaR);           // k = 2*c2+3
            }

            // np-composed score + per-row 64-lane argmin butterfly
            float nrv[8];
#pragma unroll
            for (int sl = 0; sl < 8; ++sl) nrv[sl] = nr[h * 512 + sl * 64 + cg];
#pragma unroll
            for (int r = 0; r < 8; ++r) {
                int row = row0 + r;
                float Sr = rowS[row];     // wave-local (written by own lanes 0-7)
                float t1 = 3.4e38f; int u1 = 0x7ffffff;
#pragma unroll
                for (int sl = 0; sl < 8; ++sl) {
                    int j = h * 512 + sl * 64 + cg;
                    float m2 = __fmul_rn(2.f, acc[sl][r]);
                    float sc2 = __fadd_rn(__fsub_rn(Sr, m2), nrv[sl]);
                    if (better(sc2, j, t1, u1)) { t1 = sc2; u1 = j; }
                }
#pragma unroll
                for (int off = 32; off >= 1; off >>= 1) {
                    float ob = __shfl_xor(t1, off, 64);
                    int   oj = __shfl_xor(u1, off, 64);
                    if (better(ob, oj, t1, u1)) { t1 = ob; u1 = oj; }
                }
                if (cg == r) {            // this wave owns the row: no merge
                    if (better(t1, u1, bestS[row], bestI[row])) {
                        bestS[row] = t1; bestI[row] = u1;
                    }
                }
            }
        }

        if (cg < 8) {                     // index output, wave-local rows
            int row = row0 + cg;
            out[2 + (size_t)(base + row) * KST + s] = (float)bestI[row];
        }
        __syncthreads();                  // (C) bestI final for all rows

        // residual update + loss (elementwise fp32; banks 2-way via remap)
        {
            int bi = bestI[urow];
            const float4* cp = (const float4*)(cb + (size_t)bi * DD + ug * 32);
#pragma unroll
            for (int dq = 0; dq < 8; ++dq) {
                float4 v = cp[dq];
                int d = ug * 32 + dq * 4;
                float e0 = __fsub_rn(a_t[d + 0][urow], v.x); a_t[d + 0][urow] = e0;
                float e1 = __fsub_rn(a_t[d + 1][urow], v.y); a_t[d + 1][urow] = e1;
                float e2 = __fsub_rn(a_t[d + 2][urow], v.z); a_t[d + 2][urow] = e2;
                float e3 = __fsub_rn(a_t[d + 3][urow], v.w); a_t[d + 3][urow] = e3;
                loss_acc += e0 * e0 + e1 * e1 + e2 * e2 + e3 * e3;
            }
        }
    }
    __syncthreads();                      // (E) a_t final

    // ---- outputs ---- (indices already written per stage)
    float* q = out + 2 + (size_t)NROWS * KST;
    for (int i = tid; i < ROWS * DD / 4; i += 512) {
        int row = i >> 6, dq = i & 63, d = dq * 4;
        float4 xv = ((const float4*)(x + (size_t)(base + row) * DD))[dq];
        float4 o;
        o.x = xv.x - a_t[d + 0][row];
        o.y = xv.y - a_t[d + 1][row];
        o.z = xv.z - a_t[d + 2][row];
        o.w = xv.w - a_t[d + 3][row];
        ((float4*)(q + (size_t)(base + row) * DD))[dq] = o;
    }
#pragma unroll
    for (int off = 32; off >= 1; off >>= 1) loss_acc += __shfl_down(loss_acc, off, 64);
    if ((tid & 63) == 0) wred[tid >> 6] = loss_acc;
    __syncthreads();
    if (tid == 0) {
        float t = ((wred[0] + wred[1]) + (wred[2] + wred[3]))
                + ((wred[4] + wred[5]) + (wred[6] + wred[7]));
        t *= (1.f / ((float)NROWS * (float)DD));
        atomicAdd(out + 0, t);
        atomicAdd(out + 1, t);
    }
}

// ---------------------------------------------------------------------------
extern "C" void kernel_launch(void* const* d_in, const int* in_sizes, int n_in,
                              void* d_out, int out_size, void* d_ws, size_t ws_size,
                              hipStream_t stream) {
    const float* x   = (const float*)d_in[0];   // [16,2048,256] fp32
    const float* cbs = (const float*)d_in[1];   // [8,1024,256] fp32
    float* out = (float*)d_out;
    float* n32 = (float*)d_ws;                  // 8192 floats

    hipMemsetAsync(d_out, 0, 2 * sizeof(float), stream);
    tr_kernel<<<4096, 256, 0, stream>>>(cbs);
    norms_kernel<<<32, 256, 0, stream>>>(cbs, n32);
    rvq_kernel<<<NROWS / ROWS, 512, 0, stream>>>(x, cbs, n32, out);
}